// Round 12
// baseline (207.463 us; speedup 1.0000x reference)
//
#include <hip/hip_runtime.h>

#define N_NODES 100000
#define N_EDGES 1250000
#define IN_C 64
#define HID_C 128
#define OUT_C 64
#define NBUCK 98          // ceil(N_NODES / 1024)
#define BCAP 16384        // per-bucket capacity (mean ~12755, sd ~113)
#define PA_EPT 16
#define PA_EPB (256 * PA_EPT)  // 4096 edges per block
#define PA_BLOCKS ((N_EDGES + PA_EPB - 1) / PA_EPB)  // 306
#define BB_EPT 16         // BCAP / 1024
#define CVT_X_N (N_NODES * IN_C / 4)  // 1,600,000 float4 items
#define CVT_BLOCKS ((CVT_X_N + 57344 + 255) / 256)

typedef __attribute__((ext_vector_type(8))) short short8;
typedef __attribute__((ext_vector_type(4))) float f32x4;
typedef __attribute__((ext_vector_type(2))) float f32x2;

__device__ __forceinline__ float bflo(unsigned u) { return __uint_as_float(u << 16); }
__device__ __forceinline__ float bfhi(unsigned u) { return __uint_as_float(u & 0xffff0000u); }
__device__ __forceinline__ unsigned short f2bf(float f) {
    unsigned u = __float_as_uint(f);
    return (unsigned short)((u + 0x7fffu + ((u >> 16) & 1u)) >> 16);
}
__device__ __forceinline__ unsigned packbf(float lo, float hi) {
    return ((unsigned)f2bf(hi) << 16) | f2bf(lo);
}
__device__ __forceinline__ f32x2 up2(unsigned u) {
    f32x2 r;
    r[0] = bflo(u);
    r[1] = bfhi(u);
    return r;
}
__device__ __forceinline__ void acc8p(const uint4 u, f32x2* a) {
    a[0] += up2(u.x);
    a[1] += up2(u.y);
    a[2] += up2(u.z);
    a[3] += up2(u.w);
}

#define GLOBAL_AS __attribute__((address_space(1)))
#define LDS_AS __attribute__((address_space(3)))
__device__ __forceinline__ void load_lds16(const void* g, void* l) {
    __builtin_amdgcn_global_load_lds((const GLOBAL_AS void*)g, (LDS_AS void*)l, 16, 0, 0);
}

// ---------- kernel 1: bucketize (blocks < PA_BLOCKS) + cvt (remaining blocks) ----------
__global__ __launch_bounds__(256) void bucketize_cvt_kernel(
    const unsigned int* __restrict__ e, int* __restrict__ bucketCount,
    unsigned* __restrict__ pairs, const float* __restrict__ x,
    unsigned short* __restrict__ xb, const float* __restrict__ Wl0,
    const float* __restrict__ Wr0, const float* __restrict__ Wl1,
    const float* __restrict__ Wr1, const float* __restrict__ Wo,
    unsigned short* __restrict__ wb) {
    __shared__ int cnt[NBUCK];
    __shared__ int base[NBUCK];
    __shared__ int flag_s;
    if (blockIdx.x >= PA_BLOCKS) {
        // ---- cvt section ----
        int i = (blockIdx.x - PA_BLOCKS) * 256 + threadIdx.x;
        if (i < CVT_X_N) {
            float4 v = ((const float4*)x)[i];
            unsigned lo = ((unsigned)f2bf(v.y) << 16) | f2bf(v.x);
            unsigned hi = ((unsigned)f2bf(v.w) << 16) | f2bf(v.z);
            ((uint2*)xb)[i] = make_uint2(lo, hi);
            return;
        }
        int j = i - CVT_X_N;
        if (j >= 57344) return;
        float v;
        if (j < 8192) {
            int col = j >> 6, k = j & 63;
            v = Wl0[k * HID_C + col];
        } else if (j < 16384) {
            int jj = j - 8192;
            int col = jj >> 6, k = jj & 63;
            v = Wr0[k * HID_C + col];
        } else if (j < 32768) {
            int jj = j - 16384;
            int col = jj >> 7, k = jj & 127;
            v = Wl1[k * HID_C + col];
        } else if (j < 49152) {
            int jj = j - 32768;
            int col = jj >> 7, k = jj & 127;
            v = Wr1[k * HID_C + col];
        } else {
            int jj = j - 49152;
            int col = jj >> 7, k = jj & 127;
            v = Wo[k * OUT_C + col];
        }
        wb[j] = f2bf(v);
        return;
    }
    // ---- bucketize section ----
    {
        unsigned v = e[2 * (threadIdx.x & 63) + 1];
        unsigned long long b = __ballot(v != 0u);
        if (threadIdx.x == 0) flag_s = (b == 0ull) ? 1 : 0;
    }
    for (int t = threadIdx.x; t < NBUCK; t += 256) cnt[t] = 0;
    __syncthreads();
    const bool i64 = flag_s != 0;
    const int e0 = blockIdx.x * PA_EPB;
    unsigned s[PA_EPT], d[PA_EPT];
    int rank[PA_EPT];
#pragma unroll
    for (int j = 0; j < PA_EPT; ++j) {
        int i = e0 + j * 256 + threadIdx.x;
        if (i < N_EDGES) {
            s[j] = i64 ? e[2 * i] : e[i];
            d[j] = i64 ? e[2 * (N_EDGES + i)] : e[N_EDGES + i];
            rank[j] = atomicAdd(&cnt[d[j] >> 10], 1);
        }
    }
    __syncthreads();
    for (int t = threadIdx.x; t < NBUCK; t += 256)
        base[t] = atomicAdd(&bucketCount[t], cnt[t]);
    __syncthreads();
#pragma unroll
    for (int j = 0; j < PA_EPT; ++j) {
        int i = e0 + j * 256 + threadIdx.x;
        if (i < N_EDGES) {
            unsigned b = d[j] >> 10;
            pairs[b * BCAP + base[b] + rank[j]] = s[j] | ((d[j] & 1023u) << 17);
        }
    }
}

// ---------- kernel 2: per-bucket LDS CSR build (one block per bucket) ----------
__global__ __launch_bounds__(1024) void bucket_build_kernel(
    const unsigned* __restrict__ pairs, const int* __restrict__ bucketCount,
    int* __restrict__ csr_off, int* __restrict__ csr_src) {
    __shared__ int deg[1024];
    __shared__ int sc[1024];
    __shared__ int bc[128];
    const int k = blockIdx.x;
    const int tid = threadIdx.x;
    if (tid < 128) bc[tid] = (tid < NBUCK) ? bucketCount[tid] : 0;
    deg[tid] = 0;
    __syncthreads();
    for (int off = 1; off < 128; off <<= 1) {
        int t = (tid >= off && tid < 128) ? bc[tid - off] : 0;
        __syncthreads();
        if (tid < 128) bc[tid] += t;
        __syncthreads();
    }
    const int count = bucketCount[k];
    const int gbase = bc[k] - count;
    if (k == 0 && tid == 0) csr_off[N_NODES] = N_EDGES;

    unsigned sp[BB_EPT];
    int rk[BB_EPT];
#pragma unroll
    for (int j = 0; j < BB_EPT; ++j) {
        int idx = j * 1024 + tid;
        if (idx < count) {
            unsigned u = pairs[(size_t)k * BCAP + idx];
            sp[j] = u;
            rk[j] = atomicAdd(&deg[u >> 17], 1);
        }
    }
    __syncthreads();
    const int own = deg[tid];
    sc[tid] = own;
    __syncthreads();
    for (int off = 1; off < 1024; off <<= 1) {
        int t = (tid >= off) ? sc[tid - off] : 0;
        __syncthreads();
        sc[tid] += t;
        __syncthreads();
    }
    const int excl = sc[tid] - own;
    const int node = k * 1024 + tid;
    if (node < N_NODES) csr_off[node] = gbase + excl;
    __syncthreads();
    deg[tid] = excl;
    __syncthreads();
#pragma unroll
    for (int j = 0; j < BB_EPT; ++j) {
        int idx = j * 1024 + tid;
        if (idx < count) {
            unsigned ld = sp[j] >> 17;
            csr_src[gbase + deg[ld] + rk[j]] = (int)(sp[j] & 0x1FFFFu);
        }
    }
}

// ---------- fused0: agg0 + gemm0. Block = 64 nodes, 512 threads. ----------
// Gather means -> sa LDS (swizzled); self tile -> sh via global_load_lds; MFMA.
__global__ __launch_bounds__(512) void fused0_kernel(
    const unsigned short* __restrict__ xb, const int* __restrict__ off,
    const int* __restrict__ csr_src, const unsigned short* __restrict__ WlT,
    const unsigned short* __restrict__ WrT, const float* __restrict__ b0,
    unsigned short* __restrict__ h0b) {
    __shared__ unsigned short sa[64 * IN_C];  // 8 KB mean tile (swizzled segs)
    __shared__ unsigned short sh[64 * IN_C];  // 8 KB self tile
    const int wave = threadIdx.x >> 6, lane = threadIdx.x & 63;
    const int r16 = lane & 15, q = lane >> 4;
    const int col = wave * 16 + r16;
    const int node0 = blockIdx.x * 64;

    // stage self tile (1 chunk/thread)
    {
        int t = threadIdx.x;
        int row = t >> 3, seg = t & 7;
        int grow = node0 + row;
        if (grow >= N_NODES) grow = N_NODES - 1;
        size_t soff = (size_t)grow * IN_C + (size_t)((seg ^ (row & 7)) * 8);
        load_lds16(xb + soff, sh + t * 8);
    }

    short8 bl[2], br[2];
#pragma unroll
    for (int s = 0; s < 2; ++s) {
        bl[s] = *(const short8*)(WlT + col * IN_C + s * 32 + q * 8);
        br[s] = *(const short8*)(WrT + col * IN_C + s * 32 + q * 8);
    }
    const float bias = b0[col];

    // gather phase: wave w -> nodes node0 + w*8 .. +8
    {
        const int slot = lane >> 3;  // 0..7
        const int c4 = lane & 7;     // uint4 seg within 128B row
        const uint4* base = (const uint4*)xb;
        for (int n = 0; n < 8; ++n) {
            const int wl = wave * 8 + n;  // local row
            const int wid = node0 + wl;
            f32x2 a[4] = {{0.f, 0.f}, {0.f, 0.f}, {0.f, 0.f}, {0.f, 0.f}};
            float invd = 0.f;
            if (wid < N_NODES) {
                int beg = off[wid], end = off[wid + 1];
                int e = beg + slot;
                for (; e + 8 < end; e += 16) {
                    uint4 ua = base[(size_t)csr_src[e] * 8 + c4];
                    uint4 ub = base[(size_t)csr_src[e + 8] * 8 + c4];
                    acc8p(ua, a);
                    acc8p(ub, a);
                }
                if (e < end) acc8p(base[(size_t)csr_src[e] * 8 + c4], a);
                invd = (end > beg) ? 1.f / (float)(end - beg) : 0.f;
            }
#pragma unroll
            for (int j = 0; j < 4; ++j) {
                a[j][0] += __shfl_xor(a[j][0], 8);
                a[j][1] += __shfl_xor(a[j][1], 8);
                a[j][0] += __shfl_xor(a[j][0], 16);
                a[j][1] += __shfl_xor(a[j][1], 16);
                a[j][0] += __shfl_xor(a[j][0], 32);
                a[j][1] += __shfl_xor(a[j][1], 32);
            }
            if (slot == 0) {
                uint4 o;
                o.x = packbf(a[0][0] * invd, a[0][1] * invd);
                o.y = packbf(a[1][0] * invd, a[1][1] * invd);
                o.z = packbf(a[2][0] * invd, a[2][1] * invd);
                o.w = packbf(a[3][0] * invd, a[3][1] * invd);
                *(uint4*)(&sa[wl * IN_C + ((c4 ^ (wl & 7)) * 8)]) = o;
            }
        }
    }

    asm volatile("s_waitcnt vmcnt(0)" ::: "memory");
    __syncthreads();

#pragma unroll
    for (int r = 0; r < 4; ++r) {
        const int lrow = r * 16 + r16;
        const int rsw = lrow & 7;
        short8 am[2], ax[2];
#pragma unroll
        for (int s = 0; s < 2; ++s) {
            int seg = s * 4 + q;
            int o = lrow * IN_C + ((seg ^ rsw) * 8);
            am[s] = *(const short8*)(sa + o);
            ax[s] = *(const short8*)(sh + o);
        }
        f32x4 accA, accB;
        accA[0] = bias; accA[1] = bias; accA[2] = bias; accA[3] = bias;
        accB[0] = 0.f; accB[1] = 0.f; accB[2] = 0.f; accB[3] = 0.f;
#pragma unroll
        for (int s = 0; s < 2; ++s) {
            accA = __builtin_amdgcn_mfma_f32_16x16x32_bf16(am[s], bl[s], accA, 0, 0, 0);
            accB = __builtin_amdgcn_mfma_f32_16x16x32_bf16(ax[s], br[s], accB, 0, 0, 0);
        }
#pragma unroll
        for (int rr = 0; rr < 4; ++rr) {
            int row = node0 + r * 16 + q * 4 + rr;
            if (row < N_NODES)
                h0b[(size_t)row * HID_C + col] = f2bf(fmaxf(accA[rr] + accB[rr], 0.f));
        }
    }
}

// ---------- fused1: agg1 + gemm1 + Wout projection. Block = 64 nodes. ----------
__global__ __launch_bounds__(512) void fused1_kernel(
    const unsigned short* __restrict__ h0b, const int* __restrict__ off,
    const int* __restrict__ csr_src, const unsigned short* __restrict__ WlT,
    const unsigned short* __restrict__ WrT, const unsigned short* __restrict__ WoT,
    const float* __restrict__ b1, const float* __restrict__ bo, float* __restrict__ out) {
    __shared__ unsigned short sa[64 * HID_C];   // 16 KB mean tile (swizzled)
    __shared__ unsigned short sh[64 * HID_C];   // 16 KB self tile
    __shared__ unsigned short h1s[64 * HID_C];  // 16 KB h1, XOR-swizzled
    const int wave = threadIdx.x >> 6, lane = threadIdx.x & 63;
    const int r16 = lane & 15, q = lane >> 4;
    const int col = wave * 16 + r16;
    const int node0 = blockIdx.x * 64;

    // stage self tile (2 chunks/thread)
    {
        int t = threadIdx.x;
#pragma unroll
        for (int c = 0; c < 2; ++c) {
            int idx = c * 512 + t;
            int row = idx >> 4, seg = idx & 15;
            int grow = node0 + row;
            if (grow >= N_NODES) grow = N_NODES - 1;
            size_t soff = (size_t)grow * HID_C + (size_t)((seg ^ (row & 7)) * 8);
            load_lds16(h0b + soff, sh + idx * 8);
        }
    }

    short8 bw0[4], bw1[4], wo[4];
    const int ct = wave & 3;
    const int wcol = ct * 16 + r16;
#pragma unroll
    for (int s = 0; s < 4; ++s) {
        bw0[s] = *(const short8*)(WlT + col * HID_C + s * 32 + q * 8);
        bw1[s] = *(const short8*)(WrT + col * HID_C + s * 32 + q * 8);
        wo[s] = *(const short8*)(WoT + wcol * HID_C + s * 32 + q * 8);
    }
    const float bias1 = b1[col];
    const float biaso = bo[wcol];

    // gather phase: wave w -> nodes node0 + w*8 .. +8
    {
        const int slot = lane >> 4;  // 0..3
        const int c4 = lane & 15;    // uint4 seg within 256B row
        const uint4* base = (const uint4*)h0b;
        for (int n = 0; n < 8; ++n) {
            const int wl = wave * 8 + n;
            const int wid = node0 + wl;
            f32x2 a[4] = {{0.f, 0.f}, {0.f, 0.f}, {0.f, 0.f}, {0.f, 0.f}};
            float invd = 0.f;
            if (wid < N_NODES) {
                int beg = off[wid], end = off[wid + 1];
                int e = beg + slot;
                for (; e + 4 < end; e += 8) {
                    uint4 ua = base[(size_t)csr_src[e] * 16 + c4];
                    uint4 ub = base[(size_t)csr_src[e + 4] * 16 + c4];
                    acc8p(ua, a);
                    acc8p(ub, a);
                }
                if (e < end) acc8p(base[(size_t)csr_src[e] * 16 + c4], a);
                invd = (end > beg) ? 1.f / (float)(end - beg) : 0.f;
            }
#pragma unroll
            for (int j = 0; j < 4; ++j) {
                a[j][0] += __shfl_xor(a[j][0], 16);
                a[j][1] += __shfl_xor(a[j][1], 16);
                a[j][0] += __shfl_xor(a[j][0], 32);
                a[j][1] += __shfl_xor(a[j][1], 32);
            }
            if (slot == 0) {
                uint4 o;
                o.x = packbf(a[0][0] * invd, a[0][1] * invd);
                o.y = packbf(a[1][0] * invd, a[1][1] * invd);
                o.z = packbf(a[2][0] * invd, a[2][1] * invd);
                o.w = packbf(a[3][0] * invd, a[3][1] * invd);
                *(uint4*)(&sa[wl * HID_C + ((c4 ^ (wl & 7)) * 8)]) = o;
            }
        }
    }

    asm volatile("s_waitcnt vmcnt(0)" ::: "memory");
    __syncthreads();

    // phase 1: h1 = relu(mean@Wl1 + b1 + self@Wr1) -> h1s (swizzled)
#pragma unroll
    for (int r = 0; r < 4; ++r) {
        const int lrow = r * 16 + r16;
        const int rsw = lrow & 7;
        short8 am[4], ah[4];
#pragma unroll
        for (int s = 0; s < 4; ++s) {
            int seg = s * 4 + q;
            int o = lrow * HID_C + ((seg ^ rsw) * 8);
            am[s] = *(const short8*)(sa + o);
            ah[s] = *(const short8*)(sh + o);
        }
        f32x4 accA, accB;
        accA[0] = bias1; accA[1] = bias1; accA[2] = bias1; accA[3] = bias1;
        accB[0] = 0.f; accB[1] = 0.f; accB[2] = 0.f; accB[3] = 0.f;
#pragma unroll
        for (int s = 0; s < 4; ++s) {
            accA = __builtin_amdgcn_mfma_f32_16x16x32_bf16(am[s], bw0[s], accA, 0, 0, 0);
            accB = __builtin_amdgcn_mfma_f32_16x16x32_bf16(ah[s], bw1[s], accB, 0, 0, 0);
        }
#pragma unroll
        for (int rr = 0; rr < 4; ++rr) {
            int ar = r * 16 + q * 4 + rr;
            int o = (ar * 256 + col * 2) ^ ((ar & 7) << 4);
            *(unsigned short*)((char*)h1s + o) = f2bf(fmaxf(accA[rr] + accB[rr], 0.f));
        }
    }
    __syncthreads();

    // phase 2: out = h1 @ Wout + bo
#pragma unroll
    for (int t = 0; t < 2; ++t) {
        const int rs = (wave >> 2) + 2 * t;
        f32x4 oa;
        oa[0] = biaso; oa[1] = biaso; oa[2] = biaso; oa[3] = biaso;
#pragma unroll
        for (int s = 0; s < 4; ++s) {
            int ar = rs * 16 + r16;
            int o = (ar * 256 + (s * 32 + q * 8) * 2) ^ ((ar & 7) << 4);
            short8 a = *(const short8*)((const char*)h1s + o);
            oa = __builtin_amdgcn_mfma_f32_16x16x32_bf16(a, wo[s], oa, 0, 0, 0);
        }
#pragma unroll
        for (int rr = 0; rr < 4; ++rr) {
            int row = node0 + rs * 16 + q * 4 + rr;
            if (row < N_NODES) out[(size_t)row * OUT_C + wcol] = oa[rr];
        }
    }
}

extern "C" void kernel_launch(void* const* d_in, const int* in_sizes, int n_in,
                              void* d_out, int out_size, void* d_ws, size_t ws_size,
                              hipStream_t stream) {
    const float* x = (const float*)d_in[0];
    const unsigned int* edge = (const unsigned int*)d_in[1];
    const float* Wl0 = (const float*)d_in[2];
    const float* Wr0 = (const float*)d_in[3];
    const float* bl0 = (const float*)d_in[4];
    const float* Wl1 = (const float*)d_in[5];
    const float* Wr1 = (const float*)d_in[6];
    const float* bl1 = (const float*)d_in[7];
    const float* Wo = (const float*)d_in[8];
    const float* bo = (const float*)d_in[9];
    float* out = (float*)d_out;

    char* w = (char*)d_ws;
    auto alloc = [&](size_t bytes) {
        char* p = w;
        w += (bytes + 255) & ~(size_t)255;
        return p;
    };
    int* bucketCount = (int*)alloc(NBUCK * 4);
    int* csr_off = (int*)alloc((size_t)(N_NODES + 1) * 4);
    int* csr_src = (int*)alloc((size_t)N_EDGES * 4);
    unsigned* pairs = (unsigned*)alloc((size_t)NBUCK * BCAP * 4);
    unsigned short* xb = (unsigned short*)alloc((size_t)N_NODES * IN_C * 2);
    unsigned short* h0b = (unsigned short*)alloc((size_t)N_NODES * HID_C * 2);
    unsigned short* wb = (unsigned short*)alloc(57344 * 2);

    const unsigned short* Wl0T = wb;
    const unsigned short* Wr0T = wb + 8192;
    const unsigned short* Wl1T = wb + 16384;
    const unsigned short* Wr1T = wb + 32768;
    const unsigned short* WoT = wb + 49152;

    hipMemsetAsync(bucketCount, 0, NBUCK * 4, stream);
    bucketize_cvt_kernel<<<PA_BLOCKS + CVT_BLOCKS, 256, 0, stream>>>(
        edge, bucketCount, pairs, x, xb, Wl0, Wr0, Wl1, Wr1, Wo, wb);
    bucket_build_kernel<<<NBUCK, 1024, 0, stream>>>(pairs, bucketCount, csr_off, csr_src);

    const int GEMM_BLOCKS = (N_NODES + 63) / 64;  // 1563
    fused0_kernel<<<GEMM_BLOCKS, 512, 0, stream>>>(xb, csr_off, csr_src, Wl0T, Wr0T, bl0, h0b);
    fused1_kernel<<<GEMM_BLOCKS, 512, 0, stream>>>(h0b, csr_off, csr_src, Wl1T, Wr1T, WoT, bl1,
                                                   bo, out);
}

// Round 13
// 206.021 us; speedup vs baseline: 1.0070x; 1.0070x over previous
//
#include <hip/hip_runtime.h>

#define N_NODES 100000
#define N_EDGES 1250000
#define IN_C 64
#define HID_C 128
#define OUT_C 64
#define NBUCK 98          // ceil(N_NODES / 1024)
#define BCAP 16384        // per-bucket capacity (mean ~12755, sd ~113)
#define PA_EPT 16
#define PA_EPB (256 * PA_EPT)  // 4096 edges per block
#define PA_BLOCKS ((N_EDGES + PA_EPB - 1) / PA_EPB)  // 306
#define BB_EPT 16         // BCAP / 1024
#define CVT_X_N (N_NODES * IN_C / 4)  // 1,600,000 float4 items
#define CVT_BLOCKS ((CVT_X_N + 57344 + 255) / 256)

typedef __attribute__((ext_vector_type(8))) short short8;
typedef __attribute__((ext_vector_type(4))) float f32x4;
typedef __attribute__((ext_vector_type(2))) float f32x2;

__device__ __forceinline__ float bflo(unsigned u) { return __uint_as_float(u << 16); }
__device__ __forceinline__ float bfhi(unsigned u) { return __uint_as_float(u & 0xffff0000u); }
__device__ __forceinline__ unsigned short f2bf(float f) {
    unsigned u = __float_as_uint(f);
    return (unsigned short)((u + 0x7fffu + ((u >> 16) & 1u)) >> 16);
}
__device__ __forceinline__ unsigned packbf(float lo, float hi) {
    return ((unsigned)f2bf(hi) << 16) | f2bf(lo);
}
__device__ __forceinline__ f32x2 up2(unsigned u) {
    f32x2 r;
    r[0] = bflo(u);
    r[1] = bfhi(u);
    return r;
}
__device__ __forceinline__ void acc8p(const uint4 u, f32x2* a) {
    a[0] += up2(u.x);
    a[1] += up2(u.y);
    a[2] += up2(u.z);
    a[3] += up2(u.w);
}

#define GLOBAL_AS __attribute__((address_space(1)))
#define LDS_AS __attribute__((address_space(3)))
__device__ __forceinline__ void load_lds16(const void* g, void* l) {
    __builtin_amdgcn_global_load_lds((const GLOBAL_AS void*)g, (LDS_AS void*)l, 16, 0, 0);
}

// ---------- kernel 1: bucketize (blocks < PA_BLOCKS) + cvt (remaining blocks) ----------
__global__ __launch_bounds__(256) void bucketize_cvt_kernel(
    const unsigned int* __restrict__ e, int* __restrict__ bucketCount,
    unsigned* __restrict__ pairs, const float* __restrict__ x,
    unsigned short* __restrict__ xb, const float* __restrict__ Wl0,
    const float* __restrict__ Wr0, const float* __restrict__ Wl1,
    const float* __restrict__ Wr1, const float* __restrict__ Wo,
    unsigned short* __restrict__ wb) {
    __shared__ int cnt[NBUCK];
    __shared__ int base[NBUCK];
    __shared__ int flag_s;
    if (blockIdx.x >= PA_BLOCKS) {
        int i = (blockIdx.x - PA_BLOCKS) * 256 + threadIdx.x;
        if (i < CVT_X_N) {
            float4 v = ((const float4*)x)[i];
            unsigned lo = ((unsigned)f2bf(v.y) << 16) | f2bf(v.x);
            unsigned hi = ((unsigned)f2bf(v.w) << 16) | f2bf(v.z);
            ((uint2*)xb)[i] = make_uint2(lo, hi);
            return;
        }
        int j = i - CVT_X_N;
        if (j >= 57344) return;
        float v;
        if (j < 8192) {
            int col = j >> 6, k = j & 63;
            v = Wl0[k * HID_C + col];
        } else if (j < 16384) {
            int jj = j - 8192;
            int col = jj >> 6, k = jj & 63;
            v = Wr0[k * HID_C + col];
        } else if (j < 32768) {
            int jj = j - 16384;
            int col = jj >> 7, k = jj & 127;
            v = Wl1[k * HID_C + col];
        } else if (j < 49152) {
            int jj = j - 32768;
            int col = jj >> 7, k = jj & 127;
            v = Wr1[k * HID_C + col];
        } else {
            int jj = j - 49152;
            int col = jj >> 7, k = jj & 127;
            v = Wo[k * OUT_C + col];
        }
        wb[j] = f2bf(v);
        return;
    }
    {
        unsigned v = e[2 * (threadIdx.x & 63) + 1];
        unsigned long long b = __ballot(v != 0u);
        if (threadIdx.x == 0) flag_s = (b == 0ull) ? 1 : 0;
    }
    for (int t = threadIdx.x; t < NBUCK; t += 256) cnt[t] = 0;
    __syncthreads();
    const bool i64 = flag_s != 0;
    const int e0 = blockIdx.x * PA_EPB;
    unsigned s[PA_EPT], d[PA_EPT];
    int rank[PA_EPT];
#pragma unroll
    for (int j = 0; j < PA_EPT; ++j) {
        int i = e0 + j * 256 + threadIdx.x;
        if (i < N_EDGES) {
            s[j] = i64 ? e[2 * i] : e[i];
            d[j] = i64 ? e[2 * (N_EDGES + i)] : e[N_EDGES + i];
            rank[j] = atomicAdd(&cnt[d[j] >> 10], 1);
        }
    }
    __syncthreads();
    for (int t = threadIdx.x; t < NBUCK; t += 256)
        base[t] = atomicAdd(&bucketCount[t], cnt[t]);
    __syncthreads();
#pragma unroll
    for (int j = 0; j < PA_EPT; ++j) {
        int i = e0 + j * 256 + threadIdx.x;
        if (i < N_EDGES) {
            unsigned b = d[j] >> 10;
            pairs[b * BCAP + base[b] + rank[j]] = s[j] | ((d[j] & 1023u) << 17);
        }
    }
}

// ---------- kernel 2: per-bucket LDS CSR build (one block per bucket) ----------
__global__ __launch_bounds__(1024) void bucket_build_kernel(
    const unsigned* __restrict__ pairs, const int* __restrict__ bucketCount,
    int* __restrict__ csr_off, int* __restrict__ csr_src) {
    __shared__ int deg[1024];
    __shared__ int sc[1024];
    __shared__ int bc[128];
    const int k = blockIdx.x;
    const int tid = threadIdx.x;
    if (tid < 128) bc[tid] = (tid < NBUCK) ? bucketCount[tid] : 0;
    deg[tid] = 0;
    __syncthreads();
    for (int off = 1; off < 128; off <<= 1) {
        int t = (tid >= off && tid < 128) ? bc[tid - off] : 0;
        __syncthreads();
        if (tid < 128) bc[tid] += t;
        __syncthreads();
    }
    const int count = bucketCount[k];
    const int gbase = bc[k] - count;
    if (k == 0 && tid == 0) csr_off[N_NODES] = N_EDGES;

    unsigned sp[BB_EPT];
    int rk[BB_EPT];
#pragma unroll
    for (int j = 0; j < BB_EPT; ++j) {
        int idx = j * 1024 + tid;
        if (idx < count) {
            unsigned u = pairs[(size_t)k * BCAP + idx];
            sp[j] = u;
            rk[j] = atomicAdd(&deg[u >> 17], 1);
        }
    }
    __syncthreads();
    const int own = deg[tid];
    sc[tid] = own;
    __syncthreads();
    for (int off = 1; off < 1024; off <<= 1) {
        int t = (tid >= off) ? sc[tid - off] : 0;
        __syncthreads();
        sc[tid] += t;
        __syncthreads();
    }
    const int excl = sc[tid] - own;
    const int node = k * 1024 + tid;
    if (node < N_NODES) csr_off[node] = gbase + excl;
    __syncthreads();
    deg[tid] = excl;
    __syncthreads();
#pragma unroll
    for (int j = 0; j < BB_EPT; ++j) {
        int idx = j * 1024 + tid;
        if (idx < count) {
            unsigned ld = sp[j] >> 17;
            csr_src[gbase + deg[ld] + rk[j]] = (int)(sp[j] & 0x1FFFFu);
        }
    }
}

// ---------- agg0: 8 slots x 8 lanes x uint4; batch-issue 4 loads; 4 nodes/wave ----------
__global__ __launch_bounds__(256) void agg0_kernel(
    const unsigned short* __restrict__ xb, const int* __restrict__ off,
    const int* __restrict__ csr_src, unsigned short* __restrict__ mean0b) {
    const int wave = (blockIdx.x * 256 + threadIdx.x) >> 6;
    const int lane = threadIdx.x & 63;
    const int slot = lane >> 3;  // 0..7
    const int c4 = lane & 7;     // uint4 within 128B row
    const uint4* base = (const uint4*)xb;  // 8 uint4 per row
#pragma unroll
    for (int n = 0; n < 4; ++n) {
        const int wid = wave * 4 + n;
        if (wid >= N_NODES) return;
        int beg = off[wid], end = off[wid + 1];
        f32x2 a[4] = {{0.f, 0.f}, {0.f, 0.f}, {0.f, 0.f}, {0.f, 0.f}};
        const uint4 z = {0u, 0u, 0u, 0u};
        for (int e = beg + slot; e < end; e += 32) {
            uint4 u0 = base[(size_t)csr_src[e] * 8 + c4];
            uint4 u1 = (e + 8 < end) ? base[(size_t)csr_src[e + 8] * 8 + c4] : z;
            uint4 u2 = (e + 16 < end) ? base[(size_t)csr_src[e + 16] * 8 + c4] : z;
            uint4 u3 = (e + 24 < end) ? base[(size_t)csr_src[e + 24] * 8 + c4] : z;
            acc8p(u0, a);
            acc8p(u1, a);
            acc8p(u2, a);
            acc8p(u3, a);
        }
#pragma unroll
        for (int j = 0; j < 4; ++j) {
            a[j][0] += __shfl_xor(a[j][0], 8);
            a[j][1] += __shfl_xor(a[j][1], 8);
            a[j][0] += __shfl_xor(a[j][0], 16);
            a[j][1] += __shfl_xor(a[j][1], 16);
            a[j][0] += __shfl_xor(a[j][0], 32);
            a[j][1] += __shfl_xor(a[j][1], 32);
        }
        if (slot == 0) {
            float invd = (end > beg) ? 1.f / (float)(end - beg) : 0.f;
            uint4 o;
            o.x = packbf(a[0][0] * invd, a[0][1] * invd);
            o.y = packbf(a[1][0] * invd, a[1][1] * invd);
            o.z = packbf(a[2][0] * invd, a[2][1] * invd);
            o.w = packbf(a[3][0] * invd, a[3][1] * invd);
            ((uint4*)mean0b)[(size_t)wid * 8 + c4] = o;
        }
    }
}

// ---------- agg1: 4 slots x 16 lanes x uint4; batch-issue 4 loads; 4 nodes/wave ----------
__global__ __launch_bounds__(256) void agg1_kernel(
    const unsigned short* __restrict__ h0b, const int* __restrict__ off,
    const int* __restrict__ csr_src, unsigned short* __restrict__ mean1b) {
    const int wave = (blockIdx.x * 256 + threadIdx.x) >> 6;
    const int lane = threadIdx.x & 63;
    const int slot = lane >> 4;  // 0..3
    const int c4 = lane & 15;    // uint4 within 256B row
    const uint4* base = (const uint4*)h0b;  // 16 uint4 per row
#pragma unroll
    for (int n = 0; n < 4; ++n) {
        const int wid = wave * 4 + n;
        if (wid >= N_NODES) return;
        int beg = off[wid], end = off[wid + 1];
        f32x2 a[4] = {{0.f, 0.f}, {0.f, 0.f}, {0.f, 0.f}, {0.f, 0.f}};
        const uint4 z = {0u, 0u, 0u, 0u};
        for (int e = beg + slot; e < end; e += 16) {
            uint4 u0 = base[(size_t)csr_src[e] * 16 + c4];
            uint4 u1 = (e + 4 < end) ? base[(size_t)csr_src[e + 4] * 16 + c4] : z;
            uint4 u2 = (e + 8 < end) ? base[(size_t)csr_src[e + 8] * 16 + c4] : z;
            uint4 u3 = (e + 12 < end) ? base[(size_t)csr_src[e + 12] * 16 + c4] : z;
            acc8p(u0, a);
            acc8p(u1, a);
            acc8p(u2, a);
            acc8p(u3, a);
        }
#pragma unroll
        for (int j = 0; j < 4; ++j) {
            a[j][0] += __shfl_xor(a[j][0], 16);
            a[j][1] += __shfl_xor(a[j][1], 16);
            a[j][0] += __shfl_xor(a[j][0], 32);
            a[j][1] += __shfl_xor(a[j][1], 32);
        }
        if (slot == 0) {
            float invd = (end > beg) ? 1.f / (float)(end - beg) : 0.f;
            uint4 o;
            o.x = packbf(a[0][0] * invd, a[0][1] * invd);
            o.y = packbf(a[1][0] * invd, a[1][1] * invd);
            o.z = packbf(a[2][0] * invd, a[2][1] * invd);
            o.w = packbf(a[3][0] * invd, a[3][1] * invd);
            ((uint4*)mean1b)[(size_t)wid * 16 + c4] = o;
        }
    }
}

// ---------- gemm0: h0b = relu(mean0b @ Wl0 + b0 + xb @ Wr0) ----------
__global__ __launch_bounds__(512) void gemm0_kernel(
    const unsigned short* __restrict__ mean0b, const unsigned short* __restrict__ xb,
    const unsigned short* __restrict__ WlT, const unsigned short* __restrict__ WrT,
    const float* __restrict__ b0, unsigned short* __restrict__ h0b) {
    __shared__ unsigned short sa[64 * IN_C];  // 8 KB mean tile (swizzled segs)
    __shared__ unsigned short sh[64 * IN_C];  // 8 KB self tile
    const int wave = threadIdx.x >> 6, lane = threadIdx.x & 63;
    const int r16 = lane & 15, q = lane >> 4;
    const int col = wave * 16 + r16;
    const int node0 = blockIdx.x * 64;

    {
        int t = threadIdx.x;
        int row = t >> 3, seg = t & 7;
        int grow = node0 + row;
        if (grow >= N_NODES) grow = N_NODES - 1;
        size_t soff = (size_t)grow * IN_C + (size_t)((seg ^ (row & 7)) * 8);
        load_lds16(mean0b + soff, sa + t * 8);
        load_lds16(xb + soff, sh + t * 8);
    }

    short8 bl[2], br[2];
#pragma unroll
    for (int s = 0; s < 2; ++s) {
        bl[s] = *(const short8*)(WlT + col * IN_C + s * 32 + q * 8);
        br[s] = *(const short8*)(WrT + col * IN_C + s * 32 + q * 8);
    }
    const float bias = b0[col];

    asm volatile("s_waitcnt vmcnt(0)" ::: "memory");
    __syncthreads();

#pragma unroll
    for (int r = 0; r < 4; ++r) {
        const int lrow = r * 16 + r16;
        const int rsw = lrow & 7;
        short8 am[2], ax[2];
#pragma unroll
        for (int s = 0; s < 2; ++s) {
            int seg = s * 4 + q;
            int o = lrow * IN_C + ((seg ^ rsw) * 8);
            am[s] = *(const short8*)(sa + o);
            ax[s] = *(const short8*)(sh + o);
        }
        f32x4 accA, accB;
        accA[0] = bias; accA[1] = bias; accA[2] = bias; accA[3] = bias;
        accB[0] = 0.f; accB[1] = 0.f; accB[2] = 0.f; accB[3] = 0.f;
#pragma unroll
        for (int s = 0; s < 2; ++s) {
            accA = __builtin_amdgcn_mfma_f32_16x16x32_bf16(am[s], bl[s], accA, 0, 0, 0);
            accB = __builtin_amdgcn_mfma_f32_16x16x32_bf16(ax[s], br[s], accB, 0, 0, 0);
        }
#pragma unroll
        for (int rr = 0; rr < 4; ++rr) {
            int row = node0 + r * 16 + q * 4 + rr;
            if (row < N_NODES)
                h0b[(size_t)row * HID_C + col] = f2bf(fmaxf(accA[rr] + accB[rr], 0.f));
        }
    }
}

// ---- gemm1: out = relu(mean1b@Wl1 + b1 + h0b@Wr1) @ Wout + bout ----
__global__ __launch_bounds__(512) void gemm1_kernel(
    const unsigned short* __restrict__ mean1b, const unsigned short* __restrict__ h0b,
    const unsigned short* __restrict__ WlT, const unsigned short* __restrict__ WrT,
    const unsigned short* __restrict__ WoT, const float* __restrict__ b1,
    const float* __restrict__ bo, float* __restrict__ out) {
    __shared__ unsigned short sa[64 * HID_C];   // 16 KB mean tile
    __shared__ unsigned short sh[64 * HID_C];   // 16 KB self tile
    __shared__ unsigned short h1s[64 * HID_C];  // 16 KB h1, XOR-swizzled
    const int wave = threadIdx.x >> 6, lane = threadIdx.x & 63;
    const int r16 = lane & 15, q = lane >> 4;
    const int col = wave * 16 + r16;
    const int node0 = blockIdx.x * 64;

    {
        int t = threadIdx.x;
#pragma unroll
        for (int c = 0; c < 4; ++c) {
            int idx = (c & 1) * 512 + t;
            int row = idx >> 4, seg = idx & 15;
            int grow = node0 + row;
            if (grow >= N_NODES) grow = N_NODES - 1;
            size_t soff = (size_t)grow * HID_C + (size_t)((seg ^ (row & 7)) * 8);
            if (c < 2) load_lds16(mean1b + soff, sa + idx * 8);
            else load_lds16(h0b + soff, sh + idx * 8);
        }
    }

    short8 bw0[4], bw1[4], wo[4];
    const int ct = wave & 3;
    const int wcol = ct * 16 + r16;
#pragma unroll
    for (int s = 0; s < 4; ++s) {
        bw0[s] = *(const short8*)(WlT + col * HID_C + s * 32 + q * 8);
        bw1[s] = *(const short8*)(WrT + col * HID_C + s * 32 + q * 8);
        wo[s] = *(const short8*)(WoT + wcol * HID_C + s * 32 + q * 8);
    }
    const float bias1 = b1[col];
    const float biaso = bo[wcol];

    asm volatile("s_waitcnt vmcnt(0)" ::: "memory");
    __syncthreads();

#pragma unroll
    for (int r = 0; r < 4; ++r) {
        const int lrow = r * 16 + r16;
        const int rsw = lrow & 7;
        short8 am[4], ah[4];
#pragma unroll
        for (int s = 0; s < 4; ++s) {
            int seg = s * 4 + q;
            int o = lrow * HID_C + ((seg ^ rsw) * 8);
            am[s] = *(const short8*)(sa + o);
            ah[s] = *(const short8*)(sh + o);
        }
        f32x4 accA, accB;
        accA[0] = bias1; accA[1] = bias1; accA[2] = bias1; accA[3] = bias1;
        accB[0] = 0.f; accB[1] = 0.f; accB[2] = 0.f; accB[3] = 0.f;
#pragma unroll
        for (int s = 0; s < 4; ++s) {
            accA = __builtin_amdgcn_mfma_f32_16x16x32_bf16(am[s], bw0[s], accA, 0, 0, 0);
            accB = __builtin_amdgcn_mfma_f32_16x16x32_bf16(ah[s], bw1[s], accB, 0, 0, 0);
        }
#pragma unroll
        for (int rr = 0; rr < 4; ++rr) {
            int ar = r * 16 + q * 4 + rr;
            int o = (ar * 256 + col * 2) ^ ((ar & 7) << 4);
            *(unsigned short*)((char*)h1s + o) = f2bf(fmaxf(accA[rr] + accB[rr], 0.f));
        }
    }
    __syncthreads();

#pragma unroll
    for (int t = 0; t < 2; ++t) {
        const int rs = (wave >> 2) + 2 * t;
        f32x4 oa;
        oa[0] = biaso; oa[1] = biaso; oa[2] = biaso; oa[3] = biaso;
#pragma unroll
        for (int s = 0; s < 4; ++s) {
            int ar = rs * 16 + r16;
            int o = (ar * 256 + (s * 32 + q * 8) * 2) ^ ((ar & 7) << 4);
            short8 a = *(const short8*)((const char*)h1s + o);
            oa = __builtin_amdgcn_mfma_f32_16x16x32_bf16(a, wo[s], oa, 0, 0, 0);
        }
#pragma unroll
        for (int rr = 0; rr < 4; ++rr) {
            int row = node0 + rs * 16 + q * 4 + rr;
            if (row < N_NODES) out[(size_t)row * OUT_C + wcol] = oa[rr];
        }
    }
}

extern "C" void kernel_launch(void* const* d_in, const int* in_sizes, int n_in,
                              void* d_out, int out_size, void* d_ws, size_t ws_size,
                              hipStream_t stream) {
    const float* x = (const float*)d_in[0];
    const unsigned int* edge = (const unsigned int*)d_in[1];
    const float* Wl0 = (const float*)d_in[2];
    const float* Wr0 = (const float*)d_in[3];
    const float* bl0 = (const float*)d_in[4];
    const float* Wl1 = (const float*)d_in[5];
    const float* Wr1 = (const float*)d_in[6];
    const float* bl1 = (const float*)d_in[7];
    const float* Wo = (const float*)d_in[8];
    const float* bo = (const float*)d_in[9];
    float* out = (float*)d_out;

    char* w = (char*)d_ws;
    auto alloc = [&](size_t bytes) {
        char* p = w;
        w += (bytes + 255) & ~(size_t)255;
        return p;
    };
    int* bucketCount = (int*)alloc(NBUCK * 4);
    int* csr_off = (int*)alloc((size_t)(N_NODES + 1) * 4);
    int* csr_src = (int*)alloc((size_t)N_EDGES * 4);
    unsigned* pairs = (unsigned*)alloc((size_t)NBUCK * BCAP * 4);
    unsigned short* xb = (unsigned short*)alloc((size_t)N_NODES * IN_C * 2);
    unsigned short* mean0b = (unsigned short*)alloc((size_t)N_NODES * IN_C * 2);
    unsigned short* h0b = (unsigned short*)alloc((size_t)N_NODES * HID_C * 2);
    unsigned short* mean1b = (unsigned short*)alloc((size_t)N_NODES * HID_C * 2);
    unsigned short* wb = (unsigned short*)alloc(57344 * 2);

    const unsigned short* Wl0T = wb;
    const unsigned short* Wr0T = wb + 8192;
    const unsigned short* Wl1T = wb + 16384;
    const unsigned short* Wr1T = wb + 32768;
    const unsigned short* WoT = wb + 49152;

    hipMemsetAsync(bucketCount, 0, NBUCK * 4, stream);
    bucketize_cvt_kernel<<<PA_BLOCKS + CVT_BLOCKS, 256, 0, stream>>>(
        edge, bucketCount, pairs, x, xb, Wl0, Wr0, Wl1, Wr1, Wo, wb);
    bucket_build_kernel<<<NBUCK, 1024, 0, stream>>>(pairs, bucketCount, csr_off, csr_src);

    const int AGG_BLOCKS = (N_NODES + 15) / 16;   // 6250 (4 waves x 4 nodes per block)
    const int GEMM_BLOCKS = (N_NODES + 63) / 64;  // 1563

    agg0_kernel<<<AGG_BLOCKS, 256, 0, stream>>>(xb, csr_off, csr_src, mean0b);
    gemm0_kernel<<<GEMM_BLOCKS, 512, 0, stream>>>(mean0b, xb, Wl0T, Wr0T, bl0, h0b);
    agg1_kernel<<<AGG_BLOCKS, 256, 0, stream>>>(h0b, csr_off, csr_src, mean1b);
    gemm1_kernel<<<GEMM_BLOCKS, 512, 0, stream>>>(mean1b, h0b, Wl1T, Wr1T, WoT, bl1, bo, out);
}

// Round 14
// 196.393 us; speedup vs baseline: 1.0564x; 1.0490x over previous
//
#include <hip/hip_runtime.h>

#define N_NODES 100000
#define N_EDGES 1250000
#define IN_C 64
#define HID_C 128
#define OUT_C 64
#define NBUCK 98          // ceil(N_NODES / 1024)
#define BCAP 16384        // per-bucket capacity (mean ~12755, sd ~113)
#define PA_EPT 16
#define PA_EPB (256 * PA_EPT)  // 4096 edges per block
#define PA_BLOCKS ((N_EDGES + PA_EPB - 1) / PA_EPB)  // 306
#define BB_EPT 16         // BCAP / 1024
#define CVT_X_N (N_NODES * IN_C / 4)  // 1,600,000 float4 items
#define CVT_BLOCKS ((CVT_X_N + 57344 + 255) / 256)

typedef __attribute__((ext_vector_type(8))) short short8;
typedef __attribute__((ext_vector_type(4))) float f32x4;
typedef __attribute__((ext_vector_type(2))) float f32x2;

__device__ __forceinline__ float bflo(unsigned u) { return __uint_as_float(u << 16); }
__device__ __forceinline__ float bfhi(unsigned u) { return __uint_as_float(u & 0xffff0000u); }
__device__ __forceinline__ unsigned short f2bf(float f) {
    unsigned u = __float_as_uint(f);
    return (unsigned short)((u + 0x7fffu + ((u >> 16) & 1u)) >> 16);
}
__device__ __forceinline__ unsigned packbf(float lo, float hi) {
    return ((unsigned)f2bf(hi) << 16) | f2bf(lo);
}
__device__ __forceinline__ f32x2 up2(unsigned u) {
    f32x2 r;
    r[0] = bflo(u);
    r[1] = bfhi(u);
    return r;
}
__device__ __forceinline__ void acc8p(const uint4 u, f32x2* a) {
    a[0] += up2(u.x);
    a[1] += up2(u.y);
    a[2] += up2(u.z);
    a[3] += up2(u.w);
}

#define GLOBAL_AS __attribute__((address_space(1)))
#define LDS_AS __attribute__((address_space(3)))
__device__ __forceinline__ void load_lds16(const void* g, void* l) {
    __builtin_amdgcn_global_load_lds((const GLOBAL_AS void*)g, (LDS_AS void*)l, 16, 0, 0);
}

// ---------- kernel 1: bucketize (blocks < PA_BLOCKS) + cvt (remaining blocks) ----------
__global__ __launch_bounds__(256) void bucketize_cvt_kernel(
    const unsigned int* __restrict__ e, int* __restrict__ bucketCount,
    unsigned* __restrict__ pairs, const float* __restrict__ x,
    unsigned short* __restrict__ xb, const float* __restrict__ Wl0,
    const float* __restrict__ Wr0, const float* __restrict__ Wl1,
    const float* __restrict__ Wr1, const float* __restrict__ Wo,
    unsigned short* __restrict__ wb) {
    __shared__ int cnt[NBUCK];
    __shared__ int base[NBUCK];
    __shared__ int flag_s;
    if (blockIdx.x >= PA_BLOCKS) {
        int i = (blockIdx.x - PA_BLOCKS) * 256 + threadIdx.x;
        if (i < CVT_X_N) {
            float4 v = ((const float4*)x)[i];
            unsigned lo = ((unsigned)f2bf(v.y) << 16) | f2bf(v.x);
            unsigned hi = ((unsigned)f2bf(v.w) << 16) | f2bf(v.z);
            ((uint2*)xb)[i] = make_uint2(lo, hi);
            return;
        }
        int j = i - CVT_X_N;
        if (j >= 57344) return;
        float v;
        if (j < 8192) {
            int col = j >> 6, k = j & 63;
            v = Wl0[k * HID_C + col];
        } else if (j < 16384) {
            int jj = j - 8192;
            int col = jj >> 6, k = jj & 63;
            v = Wr0[k * HID_C + col];
        } else if (j < 32768) {
            int jj = j - 16384;
            int col = jj >> 7, k = jj & 127;
            v = Wl1[k * HID_C + col];
        } else if (j < 49152) {
            int jj = j - 32768;
            int col = jj >> 7, k = jj & 127;
            v = Wr1[k * HID_C + col];
        } else {
            int jj = j - 49152;
            int col = jj >> 7, k = jj & 127;
            v = Wo[k * OUT_C + col];
        }
        wb[j] = f2bf(v);
        return;
    }
    {
        unsigned v = e[2 * (threadIdx.x & 63) + 1];
        unsigned long long b = __ballot(v != 0u);
        if (threadIdx.x == 0) flag_s = (b == 0ull) ? 1 : 0;
    }
    for (int t = threadIdx.x; t < NBUCK; t += 256) cnt[t] = 0;
    __syncthreads();
    const bool i64 = flag_s != 0;
    const int e0 = blockIdx.x * PA_EPB;
    unsigned s[PA_EPT], d[PA_EPT];
    int rank[PA_EPT];
#pragma unroll
    for (int j = 0; j < PA_EPT; ++j) {
        int i = e0 + j * 256 + threadIdx.x;
        if (i < N_EDGES) {
            s[j] = i64 ? e[2 * i] : e[i];
            d[j] = i64 ? e[2 * (N_EDGES + i)] : e[N_EDGES + i];
            rank[j] = atomicAdd(&cnt[d[j] >> 10], 1);
        }
    }
    __syncthreads();
    for (int t = threadIdx.x; t < NBUCK; t += 256)
        base[t] = atomicAdd(&bucketCount[t], cnt[t]);
    __syncthreads();
#pragma unroll
    for (int j = 0; j < PA_EPT; ++j) {
        int i = e0 + j * 256 + threadIdx.x;
        if (i < N_EDGES) {
            unsigned b = d[j] >> 10;
            pairs[b * BCAP + base[b] + rank[j]] = s[j] | ((d[j] & 1023u) << 17);
        }
    }
}

// ---------- kernel 2: per-bucket LDS CSR build (one block per bucket) ----------
__global__ __launch_bounds__(1024) void bucket_build_kernel(
    const unsigned* __restrict__ pairs, const int* __restrict__ bucketCount,
    int* __restrict__ csr_off, int* __restrict__ csr_src) {
    __shared__ int deg[1024];
    __shared__ int sc[1024];
    __shared__ int bc[128];
    const int k = blockIdx.x;
    const int tid = threadIdx.x;
    if (tid < 128) bc[tid] = (tid < NBUCK) ? bucketCount[tid] : 0;
    deg[tid] = 0;
    __syncthreads();
    for (int off = 1; off < 128; off <<= 1) {
        int t = (tid >= off && tid < 128) ? bc[tid - off] : 0;
        __syncthreads();
        if (tid < 128) bc[tid] += t;
        __syncthreads();
    }
    const int count = bucketCount[k];
    const int gbase = bc[k] - count;
    if (k == 0 && tid == 0) csr_off[N_NODES] = N_EDGES;

    unsigned sp[BB_EPT];
    int rk[BB_EPT];
#pragma unroll
    for (int j = 0; j < BB_EPT; ++j) {
        int idx = j * 1024 + tid;
        if (idx < count) {
            unsigned u = pairs[(size_t)k * BCAP + idx];
            sp[j] = u;
            rk[j] = atomicAdd(&deg[u >> 17], 1);
        }
    }
    __syncthreads();
    const int own = deg[tid];
    sc[tid] = own;
    __syncthreads();
    for (int off = 1; off < 1024; off <<= 1) {
        int t = (tid >= off) ? sc[tid - off] : 0;
        __syncthreads();
        sc[tid] += t;
        __syncthreads();
    }
    const int excl = sc[tid] - own;
    const int node = k * 1024 + tid;
    if (node < N_NODES) csr_off[node] = gbase + excl;
    __syncthreads();
    deg[tid] = excl;
    __syncthreads();
#pragma unroll
    for (int j = 0; j < BB_EPT; ++j) {
        int idx = j * 1024 + tid;
        if (idx < count) {
            unsigned ld = sp[j] >> 17;
            csr_src[gbase + deg[ld] + rk[j]] = (int)(sp[j] & 0x1FFFFu);
        }
    }
}

// ---------- agg0: 8 slots x 8 lanes x uint4 (128 B row), unroll 2; 1 node/wave ----------
__global__ __launch_bounds__(256) void agg0_kernel(
    const unsigned short* __restrict__ xb, const int* __restrict__ off,
    const int* __restrict__ csr_src, unsigned short* __restrict__ mean0b) {
    int wid = (blockIdx.x * 256 + threadIdx.x) >> 6;
    int lane = threadIdx.x & 63;
    if (wid >= N_NODES) return;
    const int slot = lane >> 3;  // 0..7
    const int c4 = lane & 7;     // uint4 within 128B row
    int beg = off[wid], end = off[wid + 1];
    const uint4* base = (const uint4*)xb;  // 8 uint4 per row
    f32x2 a[4] = {{0.f, 0.f}, {0.f, 0.f}, {0.f, 0.f}, {0.f, 0.f}};
    int e = beg + slot;
    for (; e + 8 < end; e += 16) {
        uint4 ua = base[(size_t)csr_src[e] * 8 + c4];
        uint4 ub = base[(size_t)csr_src[e + 8] * 8 + c4];
        acc8p(ua, a);
        acc8p(ub, a);
    }
    if (e < end) acc8p(base[(size_t)csr_src[e] * 8 + c4], a);
#pragma unroll
    for (int j = 0; j < 4; ++j) {
        a[j][0] += __shfl_xor(a[j][0], 8);
        a[j][1] += __shfl_xor(a[j][1], 8);
        a[j][0] += __shfl_xor(a[j][0], 16);
        a[j][1] += __shfl_xor(a[j][1], 16);
        a[j][0] += __shfl_xor(a[j][0], 32);
        a[j][1] += __shfl_xor(a[j][1], 32);
    }
    if (slot == 0) {
        float invd = (end > beg) ? 1.f / (float)(end - beg) : 0.f;
        uint4 o;
        o.x = packbf(a[0][0] * invd, a[0][1] * invd);
        o.y = packbf(a[1][0] * invd, a[1][1] * invd);
        o.z = packbf(a[2][0] * invd, a[2][1] * invd);
        o.w = packbf(a[3][0] * invd, a[3][1] * invd);
        ((uint4*)mean0b)[(size_t)wid * 8 + c4] = o;
    }
}

// ---------- agg1: 2 waves per node, each owns a 128B half-row ----------
// 8 slots x 8 lanes x uint4 per wave -> 2x the outstanding loads of the
// 4-slot full-row version (the R8->R9 slot-scaling mechanism, continued).
__global__ __launch_bounds__(256) void agg1_kernel(
    const unsigned short* __restrict__ h0b, const int* __restrict__ off,
    const int* __restrict__ csr_src, unsigned short* __restrict__ mean1b) {
    int gw = (blockIdx.x * 256 + threadIdx.x) >> 6;  // global wave id
    int wid = gw >> 1;                               // node
    int half = gw & 1;                               // which 128B half
    int lane = threadIdx.x & 63;
    if (wid >= N_NODES) return;
    const int slot = lane >> 3;       // 0..7
    const int c4 = (lane & 7) + half * 8;  // uint4 within 256B row
    int beg = off[wid], end = off[wid + 1];
    const uint4* base = (const uint4*)h0b;  // 16 uint4 per row
    f32x2 a[4] = {{0.f, 0.f}, {0.f, 0.f}, {0.f, 0.f}, {0.f, 0.f}};
    int e = beg + slot;
    for (; e + 8 < end; e += 16) {
        uint4 ua = base[(size_t)csr_src[e] * 16 + c4];
        uint4 ub = base[(size_t)csr_src[e + 8] * 16 + c4];
        acc8p(ua, a);
        acc8p(ub, a);
    }
    if (e < end) acc8p(base[(size_t)csr_src[e] * 16 + c4], a);
#pragma unroll
    for (int j = 0; j < 4; ++j) {
        a[j][0] += __shfl_xor(a[j][0], 8);
        a[j][1] += __shfl_xor(a[j][1], 8);
        a[j][0] += __shfl_xor(a[j][0], 16);
        a[j][1] += __shfl_xor(a[j][1], 16);
        a[j][0] += __shfl_xor(a[j][0], 32);
        a[j][1] += __shfl_xor(a[j][1], 32);
    }
    if (slot == 0) {
        float invd = (end > beg) ? 1.f / (float)(end - beg) : 0.f;
        uint4 o;
        o.x = packbf(a[0][0] * invd, a[0][1] * invd);
        o.y = packbf(a[1][0] * invd, a[1][1] * invd);
        o.z = packbf(a[2][0] * invd, a[2][1] * invd);
        o.w = packbf(a[3][0] * invd, a[3][1] * invd);
        ((uint4*)mean1b)[(size_t)wid * 16 + c4] = o;
    }
}

// ---------- gemm0: h0b = relu(mean0b @ Wl0 + b0 + xb @ Wr0) ----------
__global__ __launch_bounds__(512) void gemm0_kernel(
    const unsigned short* __restrict__ mean0b, const unsigned short* __restrict__ xb,
    const unsigned short* __restrict__ WlT, const unsigned short* __restrict__ WrT,
    const float* __restrict__ b0, unsigned short* __restrict__ h0b) {
    __shared__ unsigned short sa[64 * IN_C];  // 8 KB mean tile (swizzled segs)
    __shared__ unsigned short sh[64 * IN_C];  // 8 KB self tile
    const int wave = threadIdx.x >> 6, lane = threadIdx.x & 63;
    const int r16 = lane & 15, q = lane >> 4;
    const int col = wave * 16 + r16;
    const int node0 = blockIdx.x * 64;

    {
        int t = threadIdx.x;
        int row = t >> 3, seg = t & 7;
        int grow = node0 + row;
        if (grow >= N_NODES) grow = N_NODES - 1;
        size_t soff = (size_t)grow * IN_C + (size_t)((seg ^ (row & 7)) * 8);
        load_lds16(mean0b + soff, sa + t * 8);
        load_lds16(xb + soff, sh + t * 8);
    }

    short8 bl[2], br[2];
#pragma unroll
    for (int s = 0; s < 2; ++s) {
        bl[s] = *(const short8*)(WlT + col * IN_C + s * 32 + q * 8);
        br[s] = *(const short8*)(WrT + col * IN_C + s * 32 + q * 8);
    }
    const float bias = b0[col];

    asm volatile("s_waitcnt vmcnt(0)" ::: "memory");
    __syncthreads();

#pragma unroll
    for (int r = 0; r < 4; ++r) {
        const int lrow = r * 16 + r16;
        const int rsw = lrow & 7;
        short8 am[2], ax[2];
#pragma unroll
        for (int s = 0; s < 2; ++s) {
            int seg = s * 4 + q;
            int o = lrow * IN_C + ((seg ^ rsw) * 8);
            am[s] = *(const short8*)(sa + o);
            ax[s] = *(const short8*)(sh + o);
        }
        f32x4 accA, accB;
        accA[0] = bias; accA[1] = bias; accA[2] = bias; accA[3] = bias;
        accB[0] = 0.f; accB[1] = 0.f; accB[2] = 0.f; accB[3] = 0.f;
#pragma unroll
        for (int s = 0; s < 2; ++s) {
            accA = __builtin_amdgcn_mfma_f32_16x16x32_bf16(am[s], bl[s], accA, 0, 0, 0);
            accB = __builtin_amdgcn_mfma_f32_16x16x32_bf16(ax[s], br[s], accB, 0, 0, 0);
        }
#pragma unroll
        for (int rr = 0; rr < 4; ++rr) {
            int row = node0 + r * 16 + q * 4 + rr;
            if (row < N_NODES)
                h0b[(size_t)row * HID_C + col] = f2bf(fmaxf(accA[rr] + accB[rr], 0.f));
        }
    }
}

// ---- gemm1: out = relu(mean1b@Wl1 + b1 + h0b@Wr1) @ Wout + bout ----
__global__ __launch_bounds__(512) void gemm1_kernel(
    const unsigned short* __restrict__ mean1b, const unsigned short* __restrict__ h0b,
    const unsigned short* __restrict__ WlT, const unsigned short* __restrict__ WrT,
    const unsigned short* __restrict__ WoT, const float* __restrict__ b1,
    const float* __restrict__ bo, float* __restrict__ out) {
    __shared__ unsigned short sa[64 * HID_C];   // 16 KB mean tile
    __shared__ unsigned short sh[64 * HID_C];   // 16 KB self tile
    __shared__ unsigned short h1s[64 * HID_C];  // 16 KB h1, XOR-swizzled
    const int wave = threadIdx.x >> 6, lane = threadIdx.x & 63;
    const int r16 = lane & 15, q = lane >> 4;
    const int col = wave * 16 + r16;
    const int node0 = blockIdx.x * 64;

    {
        int t = threadIdx.x;
#pragma unroll
        for (int c = 0; c < 4; ++c) {
            int idx = (c & 1) * 512 + t;
            int row = idx >> 4, seg = idx & 15;
            int grow = node0 + row;
            if (grow >= N_NODES) grow = N_NODES - 1;
            size_t soff = (size_t)grow * HID_C + (size_t)((seg ^ (row & 7)) * 8);
            if (c < 2) load_lds16(mean1b + soff, sa + idx * 8);
            else load_lds16(h0b + soff, sh + idx * 8);
        }
    }

    short8 bw0[4], bw1[4], wo[4];
    const int ct = wave & 3;
    const int wcol = ct * 16 + r16;
#pragma unroll
    for (int s = 0; s < 4; ++s) {
        bw0[s] = *(const short8*)(WlT + col * HID_C + s * 32 + q * 8);
        bw1[s] = *(const short8*)(WrT + col * HID_C + s * 32 + q * 8);
        wo[s] = *(const short8*)(WoT + wcol * HID_C + s * 32 + q * 8);
    }
    const float bias1 = b1[col];
    const float biaso = bo[wcol];

    asm volatile("s_waitcnt vmcnt(0)" ::: "memory");
    __syncthreads();

#pragma unroll
    for (int r = 0; r < 4; ++r) {
        const int lrow = r * 16 + r16;
        const int rsw = lrow & 7;
        short8 am[4], ah[4];
#pragma unroll
        for (int s = 0; s < 4; ++s) {
            int seg = s * 4 + q;
            int o = lrow * HID_C + ((seg ^ rsw) * 8);
            am[s] = *(const short8*)(sa + o);
            ah[s] = *(const short8*)(sh + o);
        }
        f32x4 accA, accB;
        accA[0] = bias1; accA[1] = bias1; accA[2] = bias1; accA[3] = bias1;
        accB[0] = 0.f; accB[1] = 0.f; accB[2] = 0.f; accB[3] = 0.f;
#pragma unroll
        for (int s = 0; s < 4; ++s) {
            accA = __builtin_amdgcn_mfma_f32_16x16x32_bf16(am[s], bw0[s], accA, 0, 0, 0);
            accB = __builtin_amdgcn_mfma_f32_16x16x32_bf16(ah[s], bw1[s], accB, 0, 0, 0);
        }
#pragma unroll
        for (int rr = 0; rr < 4; ++rr) {
            int ar = r * 16 + q * 4 + rr;
            int o = (ar * 256 + col * 2) ^ ((ar & 7) << 4);
            *(unsigned short*)((char*)h1s + o) = f2bf(fmaxf(accA[rr] + accB[rr], 0.f));
        }
    }
    __syncthreads();

#pragma unroll
    for (int t = 0; t < 2; ++t) {
        const int rs = (wave >> 2) + 2 * t;
        f32x4 oa;
        oa[0] = biaso; oa[1] = biaso; oa[2] = biaso; oa[3] = biaso;
#pragma unroll
        for (int s = 0; s < 4; ++s) {
            int ar = rs * 16 + r16;
            int o = (ar * 256 + (s * 32 + q * 8) * 2) ^ ((ar & 7) << 4);
            short8 a = *(const short8*)((const char*)h1s + o);
            oa = __builtin_amdgcn_mfma_f32_16x16x32_bf16(a, wo[s], oa, 0, 0, 0);
        }
#pragma unroll
        for (int rr = 0; rr < 4; ++rr) {
            int row = node0 + rs * 16 + q * 4 + rr;
            if (row < N_NODES) out[(size_t)row * OUT_C + wcol] = oa[rr];
        }
    }
}

extern "C" void kernel_launch(void* const* d_in, const int* in_sizes, int n_in,
                              void* d_out, int out_size, void* d_ws, size_t ws_size,
                              hipStream_t stream) {
    const float* x = (const float*)d_in[0];
    const unsigned int* edge = (const unsigned int*)d_in[1];
    const float* Wl0 = (const float*)d_in[2];
    const float* Wr0 = (const float*)d_in[3];
    const float* bl0 = (const float*)d_in[4];
    const float* Wl1 = (const float*)d_in[5];
    const float* Wr1 = (const float*)d_in[6];
    const float* bl1 = (const float*)d_in[7];
    const float* Wo = (const float*)d_in[8];
    const float* bo = (const float*)d_in[9];
    float* out = (float*)d_out;

    char* w = (char*)d_ws;
    auto alloc = [&](size_t bytes) {
        char* p = w;
        w += (bytes + 255) & ~(size_t)255;
        return p;
    };
    int* bucketCount = (int*)alloc(NBUCK * 4);
    int* csr_off = (int*)alloc((size_t)(N_NODES + 1) * 4);
    int* csr_src = (int*)alloc((size_t)N_EDGES * 4);
    unsigned* pairs = (unsigned*)alloc((size_t)NBUCK * BCAP * 4);
    unsigned short* xb = (unsigned short*)alloc((size_t)N_NODES * IN_C * 2);
    unsigned short* mean0b = (unsigned short*)alloc((size_t)N_NODES * IN_C * 2);
    unsigned short* h0b = (unsigned short*)alloc((size_t)N_NODES * HID_C * 2);
    unsigned short* mean1b = (unsigned short*)alloc((size_t)N_NODES * HID_C * 2);
    unsigned short* wb = (unsigned short*)alloc(57344 * 2);

    const unsigned short* Wl0T = wb;
    const unsigned short* Wr0T = wb + 8192;
    const unsigned short* Wl1T = wb + 16384;
    const unsigned short* Wr1T = wb + 32768;
    const unsigned short* WoT = wb + 49152;

    hipMemsetAsync(bucketCount, 0, NBUCK * 4, stream);
    bucketize_cvt_kernel<<<PA_BLOCKS + CVT_BLOCKS, 256, 0, stream>>>(
        edge, bucketCount, pairs, x, xb, Wl0, Wr0, Wl1, Wr1, Wo, wb);
    bucket_build_kernel<<<NBUCK, 1024, 0, stream>>>(pairs, bucketCount, csr_off, csr_src);

    const int AGG0_BLOCKS = (N_NODES * 64 + 255) / 256;       // 25000 (1 node/wave)
    const int AGG1_BLOCKS = (N_NODES * 2 * 64 + 255) / 256;   // 50000 (2 waves/node)
    const int GEMM_BLOCKS = (N_NODES + 63) / 64;              // 1563

    agg0_kernel<<<AGG0_BLOCKS, 256, 0, stream>>>(xb, csr_off, csr_src, mean0b);
    gemm0_kernel<<<GEMM_BLOCKS, 512, 0, stream>>>(mean0b, xb, Wl0T, Wr0T, bl0, h0b);
    agg1_kernel<<<AGG1_BLOCKS, 256, 0, stream>>>(h0b, csr_off, csr_src, mean1b);
    gemm1_kernel<<<GEMM_BLOCKS, 512, 0, stream>>>(mean1b, h0b, Wl1T, Wr1T, WoT, bl1, bo, out);
}

// Round 15
// 170.068 us; speedup vs baseline: 1.2199x; 1.1548x over previous
//
#include <hip/hip_runtime.h>

#define N_NODES 100000
#define N_EDGES 1250000
#define IN_C 64
#define HID_C 128
#define OUT_C 64
#define NBUCK 196         // ceil(N_NODES / 512)
#define BCAP 8192         // per-bucket capacity (mean ~6400, sd ~80)
#define PA_EPT 16
#define PA_EPB (256 * PA_EPT)  // 4096 edges per block
#define PA_BLOCKS ((N_EDGES + PA_EPB - 1) / PA_EPB)  // 306
#define BB_EPT 16         // BCAP / 512
#define CVT_X_N (N_NODES * IN_C / 4)  // 1,600,000 float4 items
#define CVT_BLOCKS ((CVT_X_N + 57344 + 255) / 256)

typedef __attribute__((ext_vector_type(8))) short short8;
typedef __attribute__((ext_vector_type(4))) float f32x4;

__device__ __forceinline__ float bflo(unsigned u) { return __uint_as_float(u << 16); }
__device__ __forceinline__ float bfhi(unsigned u) { return __uint_as_float(u & 0xffff0000u); }
__device__ __forceinline__ unsigned short f2bf(float f) {
    unsigned u = __float_as_uint(f);
    return (unsigned short)((u + 0x7fffu + ((u >> 16) & 1u)) >> 16);
}
__device__ __forceinline__ unsigned packbf(float lo, float hi) {
    return ((unsigned)f2bf(hi) << 16) | f2bf(lo);
}
__device__ __forceinline__ void acc8(const uint4 u, float* a) {
    a[0] += bflo(u.x); a[1] += bfhi(u.x);
    a[2] += bflo(u.y); a[3] += bfhi(u.y);
    a[4] += bflo(u.z); a[5] += bfhi(u.z);
    a[6] += bflo(u.w); a[7] += bfhi(u.w);
}

#define GLOBAL_AS __attribute__((address_space(1)))
#define LDS_AS __attribute__((address_space(3)))
__device__ __forceinline__ void load_lds16(const void* g, void* l) {
    __builtin_amdgcn_global_load_lds((const GLOBAL_AS void*)g, (LDS_AS void*)l, 16, 0, 0);
}

// ---------- kernel 1: bucketize (blocks < PA_BLOCKS) + cvt (remaining blocks) ----------
// Pack: src (17 bits) | local-dst (9 bits, 512-node buckets) << 17.
__global__ __launch_bounds__(256) void bucketize_cvt_kernel(
    const unsigned int* __restrict__ e, int* __restrict__ bucketCount,
    unsigned* __restrict__ pairs, const float* __restrict__ x,
    unsigned short* __restrict__ xb, const float* __restrict__ Wl0,
    const float* __restrict__ Wr0, const float* __restrict__ Wl1,
    const float* __restrict__ Wr1, const float* __restrict__ Wo,
    unsigned short* __restrict__ wb) {
    __shared__ int cnt[NBUCK];
    __shared__ int base[NBUCK];
    __shared__ int flag_s;
    if (blockIdx.x >= PA_BLOCKS) {
        int i = (blockIdx.x - PA_BLOCKS) * 256 + threadIdx.x;
        if (i < CVT_X_N) {
            float4 v = ((const float4*)x)[i];
            unsigned lo = ((unsigned)f2bf(v.y) << 16) | f2bf(v.x);
            unsigned hi = ((unsigned)f2bf(v.w) << 16) | f2bf(v.z);
            ((uint2*)xb)[i] = make_uint2(lo, hi);
            return;
        }
        int j = i - CVT_X_N;
        if (j >= 57344) return;
        float v;
        if (j < 8192) {
            int col = j >> 6, k = j & 63;
            v = Wl0[k * HID_C + col];
        } else if (j < 16384) {
            int jj = j - 8192;
            int col = jj >> 6, k = jj & 63;
            v = Wr0[k * HID_C + col];
        } else if (j < 32768) {
            int jj = j - 16384;
            int col = jj >> 7, k = jj & 127;
            v = Wl1[k * HID_C + col];
        } else if (j < 49152) {
            int jj = j - 32768;
            int col = jj >> 7, k = jj & 127;
            v = Wr1[k * HID_C + col];
        } else {
            int jj = j - 49152;
            int col = jj >> 7, k = jj & 127;
            v = Wo[k * OUT_C + col];
        }
        wb[j] = f2bf(v);
        return;
    }
    {
        unsigned v = e[2 * (threadIdx.x & 63) + 1];
        unsigned long long b = __ballot(v != 0u);
        if (threadIdx.x == 0) flag_s = (b == 0ull) ? 1 : 0;
    }
    for (int t = threadIdx.x; t < NBUCK; t += 256) cnt[t] = 0;
    __syncthreads();
    const bool i64 = flag_s != 0;
    const int e0 = blockIdx.x * PA_EPB;
    unsigned s[PA_EPT], d[PA_EPT];
    int rank[PA_EPT];
#pragma unroll
    for (int j = 0; j < PA_EPT; ++j) {
        int i = e0 + j * 256 + threadIdx.x;
        if (i < N_EDGES) {
            s[j] = i64 ? e[2 * i] : e[i];
            d[j] = i64 ? e[2 * (N_EDGES + i)] : e[N_EDGES + i];
            rank[j] = atomicAdd(&cnt[d[j] >> 9], 1);
        }
    }
    __syncthreads();
    for (int t = threadIdx.x; t < NBUCK; t += 256)
        base[t] = atomicAdd(&bucketCount[t], cnt[t]);
    __syncthreads();
#pragma unroll
    for (int j = 0; j < PA_EPT; ++j) {
        int i = e0 + j * 256 + threadIdx.x;
        if (i < N_EDGES) {
            unsigned b = d[j] >> 9;
            pairs[b * BCAP + base[b] + rank[j]] = s[j] | ((d[j] & 511u) << 17);
        }
    }
}

// ---------- kernel 2: per-bucket LDS CSR build (196 blocks x 512 thr) ----------
__global__ __launch_bounds__(512) void bucket_build_kernel(
    const unsigned* __restrict__ pairs, const int* __restrict__ bucketCount,
    int* __restrict__ csr_off, int* __restrict__ csr_src) {
    __shared__ int deg[512];
    __shared__ int sc[512];
    __shared__ int bc[256];
    const int k = blockIdx.x;
    const int tid = threadIdx.x;
    if (tid < 256) bc[tid] = (tid < NBUCK) ? bucketCount[tid] : 0;
    deg[tid] = 0;
    __syncthreads();
    for (int off = 1; off < 256; off <<= 1) {
        int t = (tid >= off && tid < 256) ? bc[tid - off] : 0;
        __syncthreads();
        if (tid < 256) bc[tid] += t;
        __syncthreads();
    }
    const int count = bucketCount[k];
    const int gbase = bc[k] - count;
    if (k == 0 && tid == 0) csr_off[N_NODES] = N_EDGES;

    unsigned sp[BB_EPT];
    int rk[BB_EPT];
#pragma unroll
    for (int j = 0; j < BB_EPT; ++j) {
        int idx = j * 512 + tid;
        if (idx < count) {
            unsigned u = pairs[(size_t)k * BCAP + idx];
            sp[j] = u;
            rk[j] = atomicAdd(&deg[u >> 17], 1);
        }
    }
    __syncthreads();
    const int own = deg[tid];
    sc[tid] = own;
    __syncthreads();
    for (int off = 1; off < 512; off <<= 1) {
        int t = (tid >= off) ? sc[tid - off] : 0;
        __syncthreads();
        sc[tid] += t;
        __syncthreads();
    }
    const int excl = sc[tid] - own;
    const int node = k * 512 + tid;
    if (node < N_NODES) csr_off[node] = gbase + excl;
    __syncthreads();
    deg[tid] = excl;  // repurpose as exclusive-offset table
    __syncthreads();
#pragma unroll
    for (int j = 0; j < BB_EPT; ++j) {
        int idx = j * 512 + tid;
        if (idx < count) {
            unsigned ld = sp[j] >> 17;
            csr_src[gbase + deg[ld] + rk[j]] = (int)(sp[j] & 0x1FFFFu);
        }
    }
}

// ---------- agg0: 8 slots x 8 lanes x uint4 (128 B row), unroll 2; 1 node/wave ----------
__global__ __launch_bounds__(256) void agg0_kernel(
    const unsigned short* __restrict__ xb, const int* __restrict__ off,
    const int* __restrict__ csr_src, unsigned short* __restrict__ mean0b) {
    int wid = (blockIdx.x * 256 + threadIdx.x) >> 6;
    int lane = threadIdx.x & 63;
    if (wid >= N_NODES) return;
    const int slot = lane >> 3;  // 0..7
    const int c4 = lane & 7;     // uint4 within 128B row
    int beg = off[wid], end = off[wid + 1];
    const uint4* base = (const uint4*)xb;  // 8 uint4 per row
    float a[8] = {0.f, 0.f, 0.f, 0.f, 0.f, 0.f, 0.f, 0.f};
    int e = beg + slot;
    for (; e + 8 < end; e += 16) {
        uint4 ua = base[(size_t)csr_src[e] * 8 + c4];
        uint4 ub = base[(size_t)csr_src[e + 8] * 8 + c4];
        acc8(ua, a);
        acc8(ub, a);
    }
    if (e < end) acc8(base[(size_t)csr_src[e] * 8 + c4], a);
#pragma unroll
    for (int j = 0; j < 8; ++j) {
        a[j] += __shfl_xor(a[j], 8);
        a[j] += __shfl_xor(a[j], 16);
        a[j] += __shfl_xor(a[j], 32);
    }
    if (slot == 0) {
        float invd = (end > beg) ? 1.f / (float)(end - beg) : 0.f;
        uint4 o;
        o.x = packbf(a[0] * invd, a[1] * invd);
        o.y = packbf(a[2] * invd, a[3] * invd);
        o.z = packbf(a[4] * invd, a[5] * invd);
        o.w = packbf(a[6] * invd, a[7] * invd);
        ((uint4*)mean0b)[(size_t)wid * 8 + c4] = o;
    }
}

// ---------- agg1: 4 slots x 16 lanes x uint4 (256 B row), unroll 2; 1 node/wave ----------
__global__ __launch_bounds__(256) void agg1_kernel(
    const unsigned short* __restrict__ h0b, const int* __restrict__ off,
    const int* __restrict__ csr_src, unsigned short* __restrict__ mean1b) {
    int wid = (blockIdx.x * 256 + threadIdx.x) >> 6;
    int lane = threadIdx.x & 63;
    if (wid >= N_NODES) return;
    const int slot = lane >> 4;  // 0..3
    const int c4 = lane & 15;    // uint4 within 256B row
    int beg = off[wid], end = off[wid + 1];
    const uint4* base = (const uint4*)h0b;  // 16 uint4 per row
    float a[8] = {0.f, 0.f, 0.f, 0.f, 0.f, 0.f, 0.f, 0.f};
    int e = beg + slot;
    for (; e + 4 < end; e += 8) {
        uint4 ua = base[(size_t)csr_src[e] * 16 + c4];
        uint4 ub = base[(size_t)csr_src[e + 4] * 16 + c4];
        acc8(ua, a);
        acc8(ub, a);
    }
    if (e < end) acc8(base[(size_t)csr_src[e] * 16 + c4], a);
#pragma unroll
    for (int j = 0; j < 8; ++j) {
        a[j] += __shfl_xor(a[j], 16);
        a[j] += __shfl_xor(a[j], 32);
    }
    if (slot == 0) {
        float invd = (end > beg) ? 1.f / (float)(end - beg) : 0.f;
        uint4 o;
        o.x = packbf(a[0] * invd, a[1] * invd);
        o.y = packbf(a[2] * invd, a[3] * invd);
        o.z = packbf(a[4] * invd, a[5] * invd);
        o.w = packbf(a[6] * invd, a[7] * invd);
        ((uint4*)mean1b)[(size_t)wid * 16 + c4] = o;
    }
}

// ---------- gemm0: h0b = relu(mean0b @ Wl0 + b0 + xb @ Wr0) ----------
__global__ __launch_bounds__(512) void gemm0_kernel(
    const unsigned short* __restrict__ mean0b, const unsigned short* __restrict__ xb,
    const unsigned short* __restrict__ WlT, const unsigned short* __restrict__ WrT,
    const float* __restrict__ b0, unsigned short* __restrict__ h0b) {
    __shared__ unsigned short sa[64 * IN_C];  // 8 KB mean tile (swizzled segs)
    __shared__ unsigned short sh[64 * IN_C];  // 8 KB self tile
    const int wave = threadIdx.x >> 6, lane = threadIdx.x & 63;
    const int r16 = lane & 15, q = lane >> 4;
    const int col = wave * 16 + r16;
    const int node0 = blockIdx.x * 64;

    {
        int t = threadIdx.x;
        int row = t >> 3, seg = t & 7;
        int grow = node0 + row;
        if (grow >= N_NODES) grow = N_NODES - 1;
        size_t soff = (size_t)grow * IN_C + (size_t)((seg ^ (row & 7)) * 8);
        load_lds16(mean0b + soff, sa + t * 8);
        load_lds16(xb + soff, sh + t * 8);
    }

    short8 bl[2], br[2];
#pragma unroll
    for (int s = 0; s < 2; ++s) {
        bl[s] = *(const short8*)(WlT + col * IN_C + s * 32 + q * 8);
        br[s] = *(const short8*)(WrT + col * IN_C + s * 32 + q * 8);
    }
    const float bias = b0[col];

    asm volatile("s_waitcnt vmcnt(0)" ::: "memory");
    __syncthreads();

#pragma unroll
    for (int r = 0; r < 4; ++r) {
        const int lrow = r * 16 + r16;
        const int rsw = lrow & 7;
        short8 am[2], ax[2];
#pragma unroll
        for (int s = 0; s < 2; ++s) {
            int seg = s * 4 + q;
            int o = lrow * IN_C + ((seg ^ rsw) * 8);
            am[s] = *(const short8*)(sa + o);
            ax[s] = *(const short8*)(sh + o);
        }
        f32x4 accA, accB;
        accA[0] = bias; accA[1] = bias; accA[2] = bias; accA[3] = bias;
        accB[0] = 0.f; accB[1] = 0.f; accB[2] = 0.f; accB[3] = 0.f;
#pragma unroll
        for (int s = 0; s < 2; ++s) {
            accA = __builtin_amdgcn_mfma_f32_16x16x32_bf16(am[s], bl[s], accA, 0, 0, 0);
            accB = __builtin_amdgcn_mfma_f32_16x16x32_bf16(ax[s], br[s], accB, 0, 0, 0);
        }
#pragma unroll
        for (int rr = 0; rr < 4; ++rr) {
            int row = node0 + r * 16 + q * 4 + rr;
            if (row < N_NODES)
                h0b[(size_t)row * HID_C + col] = f2bf(fmaxf(accA[rr] + accB[rr], 0.f));
        }
    }
}

// ---- gemm1: out = relu(mean1b@Wl1 + b1 + h0b@Wr1) @ Wout + bout ----
__global__ __launch_bounds__(512) void gemm1_kernel(
    const unsigned short* __restrict__ mean1b, const unsigned short* __restrict__ h0b,
    const unsigned short* __restrict__ WlT, const unsigned short* __restrict__ WrT,
    const unsigned short* __restrict__ WoT, const float* __restrict__ b1,
    const float* __restrict__ bo, float* __restrict__ out) {
    __shared__ unsigned short sa[64 * HID_C];   // 16 KB mean tile
    __shared__ unsigned short sh[64 * HID_C];   // 16 KB self tile
    __shared__ unsigned short h1s[64 * HID_C];  // 16 KB h1, XOR-swizzled
    const int wave = threadIdx.x >> 6, lane = threadIdx.x & 63;
    const int r16 = lane & 15, q = lane >> 4;
    const int col = wave * 16 + r16;
    const int node0 = blockIdx.x * 64;

    {
        int t = threadIdx.x;
#pragma unroll
        for (int c = 0; c < 4; ++c) {
            int idx = (c & 1) * 512 + t;
            int row = idx >> 4, seg = idx & 15;
            int grow = node0 + row;
            if (grow >= N_NODES) grow = N_NODES - 1;
            size_t soff = (size_t)grow * HID_C + (size_t)((seg ^ (row & 7)) * 8);
            if (c < 2) load_lds16(mean1b + soff, sa + idx * 8);
            else load_lds16(h0b + soff, sh + idx * 8);
        }
    }

    short8 bw0[4], bw1[4], wo[4];
    const int ct = wave & 3;
    const int wcol = ct * 16 + r16;
#pragma unroll
    for (int s = 0; s < 4; ++s) {
        bw0[s] = *(const short8*)(WlT + col * HID_C + s * 32 + q * 8);
        bw1[s] = *(const short8*)(WrT + col * HID_C + s * 32 + q * 8);
        wo[s] = *(const short8*)(WoT + wcol * HID_C + s * 32 + q * 8);
    }
    const float bias1 = b1[col];
    const float biaso = bo[wcol];

    asm volatile("s_waitcnt vmcnt(0)" ::: "memory");
    __syncthreads();

#pragma unroll
    for (int r = 0; r < 4; ++r) {
        const int lrow = r * 16 + r16;
        const int rsw = lrow & 7;
        short8 am[4], ah[4];
#pragma unroll
        for (int s = 0; s < 4; ++s) {
            int seg = s * 4 + q;
            int o = lrow * HID_C + ((seg ^ rsw) * 8);
            am[s] = *(const short8*)(sa + o);
            ah[s] = *(const short8*)(sh + o);
        }
        f32x4 accA, accB;
        accA[0] = bias1; accA[1] = bias1; accA[2] = bias1; accA[3] = bias1;
        accB[0] = 0.f; accB[1] = 0.f; accB[2] = 0.f; accB[3] = 0.f;
#pragma unroll
        for (int s = 0; s < 4; ++s) {
            accA = __builtin_amdgcn_mfma_f32_16x16x32_bf16(am[s], bw0[s], accA, 0, 0, 0);
            accB = __builtin_amdgcn_mfma_f32_16x16x32_bf16(ah[s], bw1[s], accB, 0, 0, 0);
        }
#pragma unroll
        for (int rr = 0; rr < 4; ++rr) {
            int ar = r * 16 + q * 4 + rr;
            int o = (ar * 256 + col * 2) ^ ((ar & 7) << 4);
            *(unsigned short*)((char*)h1s + o) = f2bf(fmaxf(accA[rr] + accB[rr], 0.f));
        }
    }
    __syncthreads();

#pragma unroll
    for (int t = 0; t < 2; ++t) {
        const int rs = (wave >> 2) + 2 * t;
        f32x4 oa;
        oa[0] = biaso; oa[1] = biaso; oa[2] = biaso; oa[3] = biaso;
#pragma unroll
        for (int s = 0; s < 4; ++s) {
            int ar = rs * 16 + r16;
            int o = (ar * 256 + (s * 32 + q * 8) * 2) ^ ((ar & 7) << 4);
            short8 a = *(const short8*)((const char*)h1s + o);
            oa = __builtin_amdgcn_mfma_f32_16x16x32_bf16(a, wo[s], oa, 0, 0, 0);
        }
#pragma unroll
        for (int rr = 0; rr < 4; ++rr) {
            int row = node0 + rs * 16 + q * 4 + rr;
            if (row < N_NODES) out[(size_t)row * OUT_C + wcol] = oa[rr];
        }
    }
}

extern "C" void kernel_launch(void* const* d_in, const int* in_sizes, int n_in,
                              void* d_out, int out_size, void* d_ws, size_t ws_size,
                              hipStream_t stream) {
    const float* x = (const float*)d_in[0];
    const unsigned int* edge = (const unsigned int*)d_in[1];
    const float* Wl0 = (const float*)d_in[2];
    const float* Wr0 = (const float*)d_in[3];
    const float* bl0 = (const float*)d_in[4];
    const float* Wl1 = (const float*)d_in[5];
    const float* Wr1 = (const float*)d_in[6];
    const float* bl1 = (const float*)d_in[7];
    const float* Wo = (const float*)d_in[8];
    const float* bo = (const float*)d_in[9];
    float* out = (float*)d_out;

    char* w = (char*)d_ws;
    auto alloc = [&](size_t bytes) {
        char* p = w;
        w += (bytes + 255) & ~(size_t)255;
        return p;
    };
    int* bucketCount = (int*)alloc(NBUCK * 4);
    int* csr_off = (int*)alloc((size_t)(N_NODES + 1) * 4);
    int* csr_src = (int*)alloc((size_t)N_EDGES * 4);
    unsigned* pairs = (unsigned*)alloc((size_t)NBUCK * BCAP * 4);
    unsigned short* xb = (unsigned short*)alloc((size_t)N_NODES * IN_C * 2);
    unsigned short* mean0b = (unsigned short*)alloc((size_t)N_NODES * IN_C * 2);
    unsigned short* h0b = (unsigned short*)alloc((size_t)N_NODES * HID_C * 2);
    unsigned short* mean1b = (unsigned short*)alloc((size_t)N_NODES * HID_C * 2);
    unsigned short* wb = (unsigned short*)alloc(57344 * 2);

    const unsigned short* Wl0T = wb;
    const unsigned short* Wr0T = wb + 8192;
    const unsigned short* Wl1T = wb + 16384;
    const unsigned short* Wr1T = wb + 32768;
    const unsigned short* WoT = wb + 49152;

    hipMemsetAsync(bucketCount, 0, NBUCK * 4, stream);
    bucketize_cvt_kernel<<<PA_BLOCKS + CVT_BLOCKS, 256, 0, stream>>>(
        edge, bucketCount, pairs, x, xb, Wl0, Wr0, Wl1, Wr1, Wo, wb);
    bucket_build_kernel<<<NBUCK, 512, 0, stream>>>(pairs, bucketCount, csr_off, csr_src);

    const int AGG_BLOCKS = (N_NODES * 64 + 255) / 256;  // 25000 (1 node/wave)
    const int GEMM_BLOCKS = (N_NODES + 63) / 64;        // 1563

    agg0_kernel<<<AGG_BLOCKS, 256, 0, stream>>>(xb, csr_off, csr_src, mean0b);
    gemm0_kernel<<<GEMM_BLOCKS, 512, 0, stream>>>(mean0b, xb, Wl0T, Wr0T, bl0, h0b);
    agg1_kernel<<<AGG_BLOCKS, 256, 0, stream>>>(h0b, csr_off, csr_src, mean1b);
    gemm1_kernel<<<GEMM_BLOCKS, 512, 0, stream>>>(mean1b, h0b, Wl1T, Wr1T, WoT, bl1, bo, out);
}